// Round 13
// baseline (16615.649 us; speedup 1.0000x reference)
//
#include <hip/hip_runtime.h>

#define HIDDEN   2048
#define T_STEPS  8192
#define WASHOUT  200
#define NWG      128
#define NTHR     512
#define NWAVE    (NTHR / 64)                 // 8 waves
#define ROWS_PER_WG   (HIDDEN / NWG)         // 16
#define ROWS_PER_WAVE (ROWS_PER_WG / NWAVE)  // 2
#define NCHUNK   8                           // 8 staging chunks of 256 pairs
#define NREPL    8                           // one mailbox replica per XCD
#define REPL     (2 * HIDDEN)                // ull elements per replica (32 KB)

// ws layout: NREPL replicas of {unsigned long long pairs[2][HIDDEN]}.
// Pair = {value:hi32, step:lo32}; 0xAA poison tags self-correct across
// graph replays (stale end-of-run tags never match the restarted want
// sequence before being overwritten).
//
// R26 (this round): 128 WORKGROUPS x 16 ROWS -- the one compute-thinning
// path that avoids the register cap. R8/R11 failed because 1024-thr caps
// regs at 128 and regalloc parks weights in AGPRs; this keeps the proven
// 512-thr/8-wave/256-reg shape and halves rows/WG instead. Post-detect
// serial tail (proven fully exposed by R7's -13.5% tail shave): 64 FMAs +
// 4 ds_read_b128 per thread instead of 128 + 8. Staging/poll per wave,
// replicas, publish protocol, reduce, fast tanh: unchanged.
// Named risks: slowest-of-128 publisher jitter; 2x spin load per XCD L2;
// publish = 128B full-line stores (R1's partial-line failure N/A).
// Pre-registered: <=13.6ms keep; 13.8-14.3 neutral -> revert+ROOFLINE;
// >=14.5 contention -> revert+ROOFLINE.
//
// Falsified this session: scatter publish (R1), nt polls (R2, 1.6x),
// single-XCD (R3), in-order LDS flags (R4), nt publish (R4), serial
// subgroup poll (R9), OoO consume-during-spin (R10), 16-wave (R8/R11).
// Confirmed: per-XCD replicas (R5, -8%), tail shave (R7, -13.5%).

// DPP add: x + dpp_perm(x). All-VALU (no DS round trip).
#define DPP_ADD(x, ctrl) ((x) + __int_as_float(__builtin_amdgcn_update_dpp( \
    0, __float_as_int(x), ctrl, 0xF, 0xF, true)))

typedef unsigned uint4v __attribute__((ext_vector_type(4)));
typedef unsigned uint2v __attribute__((ext_vector_type(2)));

// 64-lane sum via permlane{16,32}_swap self-swap (both outputs summed ->
// direction-agnostic). Builtin form only: R19's asm form let the allocator
// coalesce the two same-value "+v" operands into one register.
#define PERMLANE_SUM_1632(h)                                         \
  {                                                                  \
    uint2v s16 = __builtin_amdgcn_permlane16_swap(                   \
        __float_as_uint(h), __float_as_uint(h), false, false);       \
    h = __uint_as_float(s16.x) + __uint_as_float(s16.y);             \
    uint2v s32 = __builtin_amdgcn_permlane32_swap(                   \
        __float_as_uint(h), __float_as_uint(h), false, false);       \
    h = __uint_as_float(s32.x) + __uint_as_float(s32.y);             \
  }

__global__ __launch_bounds__(NTHR, 1) void esn_main(
    const float* __restrict__ u,
    const float* __restrict__ w_in,
    const float* __restrict__ w_res,
    const float* __restrict__ w_out,
    float* __restrict__ out,
    unsigned long long* __restrict__ pairs,
    int nrepl)
{
  const int g  = blockIdx.x;    // 0..127, one WG per CU (128 of 256 CUs)
  const int j  = threadIdx.x;   // 0..511
  const int wv = j >> 6;        // 0..7
  const int l  = j & 63;

  // which XCD am I on? poll only that replica. Uniform per wave (SGPR).
  unsigned xcc;
  asm("s_getreg_b32 %0, hwreg(HW_REG_XCC_ID)" : "=s"(xcc));
  const unsigned ri = xcc & (unsigned)(nrepl - 1);   // nrepl is 1 or 8
  unsigned long long* __restrict__ myrep = pairs + (size_t)ri * REPL;

  __shared__ float x_s[2][HIDDEN];      // double-buffered staged state (16 KB)
  __shared__ float u_s[T_STEPS];        // 32 KB
  __shared__ float fresh[ROWS_PER_WG];  // this WG's newest 16 values

#pragma unroll
  for (int k = 0; k < T_STEPS / NTHR; ++k) u_s[j + NTHR * k] = u[j + NTHR * k];

  // wave wv owns rows r0..r0+1; lane l owns cols {c*256 + 4l .. +3}
  const int r0 = g * ROWS_PER_WG + wv * ROWS_PER_WAVE;

  float wreg[ROWS_PER_WAVE][4 * NCHUNK];  // 64 register-resident weights
#pragma unroll
  for (int i = 0; i < ROWS_PER_WAVE; ++i) {
#pragma unroll
    for (int c = 0; c < NCHUNK; ++c) {
      const float4 a = *(const float4*)&w_res[(r0 + i) * HIDDEN + c * 256 + 4 * l];
      wreg[i][4 * c + 0] = a.x; wreg[i][4 * c + 1] = a.y;
      wreg[i][4 * c + 2] = a.z; wreg[i][4 * c + 3] = a.w;
    }
  }
  // pin weights; value becomes opaque -> no refetch, no remat in t-loop
#pragma unroll
  for (int i = 0; i < ROWS_PER_WAVE; ++i)
#pragma unroll
    for (int k = 0; k < 4 * NCHUNK; ++k)
      asm volatile("" : "+v"(wreg[i][k]));

  const float winl = w_in[r0 + (l & 1)];                             // lanes 0..1
  const float wol  = (wv == 1 && l < ROWS_PER_WG)
                     ? w_out[g * ROWS_PER_WG + l] : 0.f;             // wave 1

  __syncthreads();  // u_s ready

  for (int t = 0; t < T_STEPS; ++t) {
    float d0 = 0.f, d1 = 0.f;
    const unsigned b = (unsigned)((t - 1) & 1);
    if (t > 0) {
      const unsigned want = (unsigned)(t - 1);
      // wave wv polls its 256-pair chunk OF ITS XCD'S REPLICA;
      // 2x16B sc1 loads -> spin served from the local L2. (Identical
      // per-wave pattern to R7; only the publisher count changed.)
      const unsigned long long* bp = myrep + b * HIDDEN + (wv << 8) + 4 * l;
      uint4v A, B;   // [tag0, val0, tag1, val1]
      for (;;) {
        asm volatile(
            "global_load_dwordx4 %0, %2, off sc1\n\t"
            "global_load_dwordx4 %1, %3, off sc1\n\t"
            "s_waitcnt vmcnt(0)"
            : "=&v"(A), "=&v"(B)
            : "v"(bp), "v"(bp + 2)
            : "memory");
        if (((A.x == want) & (A.z == want)) &
            ((B.x == want) & (B.z == want))) break;
      }
      float4 xv;
      xv.x = __uint_as_float(A.y);
      xv.y = __uint_as_float(A.w);
      xv.z = __uint_as_float(B.y);
      xv.w = __uint_as_float(B.w);
      *(float4*)&x_s[b][(wv << 8) + 4 * l] = xv;  // one ds_write_b128
    }
    __syncthreads();  // barrier 1: all chunks staged

    if (t > 0) {
      const float4* xs4 = (const float4*)x_s[b];
#pragma unroll
      for (int c = 0; c < NCHUNK; ++c) {
        const float4 x4 = xs4[(c << 6) + l];   // ds_read_b128
        d0 = fmaf(wreg[0][4 * c + 0], x4.x, d0);
        d0 = fmaf(wreg[0][4 * c + 1], x4.y, d0);
        d0 = fmaf(wreg[0][4 * c + 2], x4.z, d0);
        d0 = fmaf(wreg[0][4 * c + 3], x4.w, d0);
        d1 = fmaf(wreg[1][4 * c + 0], x4.x, d1);
        d1 = fmaf(wreg[1][4 * c + 1], x4.y, d1);
        d1 = fmaf(wreg[1][4 * c + 2], x4.z, d1);
        d1 = fmaf(wreg[1][4 * c + 3], x4.w, d1);
      }
    }

    // reduce: parity-preserving all-VALU chain (R8-proven for 2 rows).
    // After xor1+select, even lanes carry row0 partials, odd lanes row1;
    // xor2/ror4/ror8/swap16/swap32 preserve parity -> lane0=r0, lane1=r0+1.
    float e0 = DPP_ADD(d0, 0xB1);   // quad_perm [1,0,3,2]  (xor 1)
    float e1 = DPP_ADD(d1, 0xB1);
    float h = (l & 1) ? e1 : e0;
    h = DPP_ADD(h, 0x4E);           // quad_perm [2,3,0,1]  (xor 2)
    h = DPP_ADD(h, 0x124);          // row_ror:4
    h = DPP_ADD(h, 0x128);          // row_ror:8
    PERMLANE_SUM_1632(h)

    const float ut = u_s[t];
    if (l < ROWS_PER_WAVE) {
      // fast tanh: 1 - 2/(e^{2x}+1) via v_exp_f32 (2^x) + v_rcp_f32;
      // saturates correctly; ~1e-6 abs err (R7-proven).
      const float a = fmaf(winl, ut, h);
      float z;
      asm("v_exp_f32 %0, %1" : "=v"(z) : "v"(a * 2.885390082f));
      float r;
      asm("v_rcp_f32 %0, %1" : "=v"(r) : "v"(z + 1.0f));
      fresh[wv * ROWS_PER_WAVE + l] = fmaf(-2.0f, r, 1.0f);
    }
    __syncthreads();  // barrier 2: fresh[] complete

    // per-wave replica publish: wave wv stores the WG's full 16-row slice
    // to replica wv -- one 16-lane 128B FULL-LINE store per wave
    // (aligned at g*128B), 8 replicas covered by 8 waves in parallel.
    if (wv < nrepl && l < ROWS_PER_WG) {
      const unsigned long long pk =
          ((unsigned long long)__float_as_uint(fresh[l]) << 32) | (unsigned)t;
      __hip_atomic_store(
          pairs + (size_t)wv * REPL + (t & 1) * HIDDEN + g * ROWS_PER_WG + l,
          pk, __ATOMIC_RELAXED, __HIP_MEMORY_SCOPE_AGENT);
    }
    if (wv == 1 && t >= WASHOUT) {
      // distributed readout: this WG's 16-row partial of x_t . w_out,
      // all-VALU reduce (lanes >= 16 contribute 0).
      float part = (l < ROWS_PER_WG) ? fresh[l] * wol : 0.f;
      part = DPP_ADD(part, 0xB1);
      part = DPP_ADD(part, 0x4E);
      part = DPP_ADD(part, 0x124);
      part = DPP_ADD(part, 0x128);
      PERMLANE_SUM_1632(part)
      if (l == 0) atomicAdd(&out[t - WASHOUT], part);
    }
  }
}

extern "C" void kernel_launch(void* const* d_in, const int* in_sizes, int n_in,
                              void* d_out, int out_size, void* d_ws, size_t ws_size,
                              hipStream_t stream) {
  const float* u     = (const float*)d_in[0];
  const float* w_in  = (const float*)d_in[1];
  const float* w_res = (const float*)d_in[2];
  const float* w_out = (const float*)d_in[3];
  float* out = (float*)d_out;
  unsigned long long* pairs = (unsigned long long*)d_ws;

  // replicas need NREPL * 32 KB of ws; fall back to a single mailbox
  const int nrepl =
      (ws_size >= (size_t)NREPL * REPL * sizeof(unsigned long long)) ? NREPL : 1;

  // out accumulates atomicAdd partials -> must start at zero every call
  hipMemsetAsync(out, 0, (size_t)out_size * sizeof(float), stream);
  esn_main<<<NWG, NTHR, 0, stream>>>(u, w_in, w_res, w_out, out, pairs, nrepl);
}

// Round 14
// 14065.005 us; speedup vs baseline: 1.1813x; 1.1813x over previous
//
#include <hip/hip_runtime.h>

#define HIDDEN   2048
#define T_STEPS  8192
#define WASHOUT  200
#define NWG      64
#define NTHR     512
#define NWAVE    (NTHR / 64)                 // 8 waves
#define ROWS_PER_WG   (HIDDEN / NWG)         // 32
#define ROWS_PER_WAVE (ROWS_PER_WG / NWAVE)  // 4
#define NCHUNK   8                           // 8 chunks of 256 state elements
#define NREPL    8                           // one mailbox replica per XCD
#define REPL     (2 * HIDDEN)                // ull elements per replica (32 KB)

// ws layout: NREPL replicas of {unsigned long long pairs[2][HIDDEN]}.
// Pair = {value:hi32, step:lo32}: one 8B unit carries payload+tag.
// 0xAA poison tags self-correct across graph replays.
//
// R27 (FINAL): exact revert to the R7/R12 winner (14.05 ms, verified
// twice: R7=14.06, R12=14.05). R13's 128-WG thinning regressed to 16.62ms
// (VGPR=48: AGPR parking even at 512thr for that shape; slowest-of-128
// publisher jitter; 2x L2 spin pressure) -- the last untested structural
// axis is falsified and the floor claim is structural:
// ~0.55-1.0us/step cross-XCD store->invalidate->refetch (coherence
// protocol floor at 64 communicating nodes) + ~0.6us FMA/stage/reduce
// that the register file cannot thin further.
//
// Session falsification set (each probed from both directions):
//   publish: R1 scatter X | R5 per-XCD replicas OK (-8%)
//   caching: R2 nt polls X (1.6x) | sc1 local-L2 spin OK
//   locality: R3 single-XCD X (register-file arithmetic)
//   barriers: R4 in-order flags X, R9 serial subgroups X, R10 OoO X
//   thread shape: R8/R11 1024-thr X (AGPR cap), R13 128-WG X (jitter)
//   serial tail: R7 permlane+fast-tanh+per-wave-publish OK (-13.5%)

// DPP add: x + dpp_perm(x). All-VALU (no DS round trip).
#define DPP_ADD(x, ctrl) ((x) + __int_as_float(__builtin_amdgcn_update_dpp( \
    0, __float_as_int(x), ctrl, 0xF, 0xF, true)))

typedef unsigned uint4v __attribute__((ext_vector_type(4)));
typedef unsigned uint2v __attribute__((ext_vector_type(2)));

__global__ __launch_bounds__(NTHR, 1) void esn_main(
    const float* __restrict__ u,
    const float* __restrict__ w_in,
    const float* __restrict__ w_res,
    const float* __restrict__ w_out,
    float* __restrict__ out,
    unsigned long long* __restrict__ pairs,
    int nrepl)
{
  const int g  = blockIdx.x;    // 0..63, one WG per CU
  const int j  = threadIdx.x;   // 0..511
  const int wv = j >> 6;        // 0..7
  const int l  = j & 63;

  // which XCD am I on? poll only that replica. Uniform per wave (SGPR).
  unsigned xcc;
  asm("s_getreg_b32 %0, hwreg(HW_REG_XCC_ID)" : "=s"(xcc));
  const unsigned ri = xcc & (unsigned)(nrepl - 1);   // nrepl is 1 or 8
  unsigned long long* __restrict__ myrep = pairs + (size_t)ri * REPL;

  __shared__ float x_s[2][HIDDEN];      // double-buffered staged state (16 KB)
  __shared__ float u_s[T_STEPS];        // 32 KB
  __shared__ float fresh[ROWS_PER_WG];  // this WG's newest 32 values

#pragma unroll
  for (int k = 0; k < T_STEPS / NTHR; ++k) u_s[j + NTHR * k] = u[j + NTHR * k];

  // wave wv owns rows r0..r0+3; lane l owns cols {c*256 + 4l .. +3}
  const int r0 = g * ROWS_PER_WG + wv * ROWS_PER_WAVE;

  float wreg[ROWS_PER_WAVE][4 * NCHUNK];  // 128 register-resident weights
#pragma unroll
  for (int i = 0; i < ROWS_PER_WAVE; ++i) {
#pragma unroll
    for (int c = 0; c < NCHUNK; ++c) {
      const float4 a = *(const float4*)&w_res[(r0 + i) * HIDDEN + c * 256 + 4 * l];
      wreg[i][4 * c + 0] = a.x; wreg[i][4 * c + 1] = a.y;
      wreg[i][4 * c + 2] = a.z; wreg[i][4 * c + 3] = a.w;
    }
  }
  // pin weights; value becomes opaque -> no refetch, no remat in t-loop
#pragma unroll
  for (int i = 0; i < ROWS_PER_WAVE; ++i)
#pragma unroll
    for (int k = 0; k < 4 * NCHUNK; ++k)
      asm volatile("" : "+v"(wreg[i][k]));

  const float winl = w_in[r0 + (l & 3)];                             // lanes 0..3
  const float wol  = (wv == 1 && l < 32) ? w_out[g * 32 + l] : 0.f;  // wave 1

  __syncthreads();  // u_s ready

  for (int t = 0; t < T_STEPS; ++t) {
    float d0 = 0.f, d1 = 0.f, d2 = 0.f, d3 = 0.f;
    const unsigned b = (unsigned)((t - 1) & 1);
    if (t > 0) {
      const unsigned want = (unsigned)(t - 1);
      // wave wv polls only its own chunk OF ITS XCD'S REPLICA;
      // 2x16B sc1 loads -> spin served from the local L2.
      const unsigned long long* bp = myrep + b * HIDDEN + (wv << 8) + 4 * l;
      uint4v A, B;   // [tag0, val0, tag1, val1]
      for (;;) {
        asm volatile(
            "global_load_dwordx4 %0, %2, off sc1\n\t"
            "global_load_dwordx4 %1, %3, off sc1\n\t"
            "s_waitcnt vmcnt(0)"
            : "=&v"(A), "=&v"(B)
            : "v"(bp), "v"(bp + 2)
            : "memory");
        if (((A.x == want) & (A.z == want)) &
            ((B.x == want) & (B.z == want))) break;
      }
      float4 xv;
      xv.x = __uint_as_float(A.y);
      xv.y = __uint_as_float(A.w);
      xv.z = __uint_as_float(B.y);
      xv.w = __uint_as_float(B.w);
      *(float4*)&x_s[b][(wv << 8) + 4 * l] = xv;  // one ds_write_b128
    }
    __syncthreads();  // barrier 1: all chunks staged

    if (t > 0) {
      const float4* xs4 = (const float4*)x_s[b];
#define ROWFMA(i, di)                            \
      di = fmaf(wreg[i][4*c+0], x4.x, di);       \
      di = fmaf(wreg[i][4*c+1], x4.y, di);       \
      di = fmaf(wreg[i][4*c+2], x4.z, di);       \
      di = fmaf(wreg[i][4*c+3], x4.w, di);
#pragma unroll
      for (int c = 0; c < NCHUNK; ++c) {
        const float4 x4 = xs4[(c << 6) + l];   // ds_read_b128
        ROWFMA(0, d0)
        ROWFMA(1, d1)
        ROWFMA(2, d2)
        ROWFMA(3, d3)
      }
#undef ROWFMA
    }

    // reduce: DPP for intra-16 steps; permlane swaps (pure VALU, no LDS
    // round trip) for the 16/32 cross-group steps.
    float e0 = DPP_ADD(d0, 0xB1);   // quad_perm [1,0,3,2]  (xor 1)
    float e1 = DPP_ADD(d1, 0xB1);
    float e2 = DPP_ADD(d2, 0xB1);
    float e3 = DPP_ADD(d3, 0xB1);
    float f0 = (l & 1) ? e1 : e0;
    float f1 = (l & 1) ? e3 : e2;
    f0 = DPP_ADD(f0, 0x4E);         // quad_perm [2,3,0,1]  (xor 2)
    f1 = DPP_ADD(f1, 0x4E);
    float h = (l & 2) ? f1 : f0;
    h = DPP_ADD(h, 0x124);          // row_ror:4
    h = DPP_ADD(h, 0x128);          // row_ror:8
#if __has_builtin(__builtin_amdgcn_permlane16_swap) && \
    __has_builtin(__builtin_amdgcn_permlane32_swap)
    {
      // h += h^16 then h += h^32. Builtin returns BOTH outputs (uint2) ->
      // distinct registers guaranteed (R19's asm self-swap coalesced the
      // two "+v" operands into one reg and corrupted the sums).
      uint2v s16 = __builtin_amdgcn_permlane16_swap(
          __float_as_uint(h), __float_as_uint(h), false, false);
      h = __uint_as_float(s16.x) + __uint_as_float(s16.y);
      uint2v s32 = __builtin_amdgcn_permlane32_swap(
          __float_as_uint(h), __float_as_uint(h), false, false);
      h = __uint_as_float(s32.x) + __uint_as_float(s32.y);
    }
#else
    h += __shfl_xor(h, 16, 64);
    h += __shfl_xor(h, 32, 64);
#endif

    const float ut = u_s[t];
    if (l < ROWS_PER_WAVE) {
      // fast tanh: 1 - 2/(e^{2x}+1) via v_exp_f32 (2^x) + v_rcp_f32;
      // saturates correctly via exp overflow/underflow; ~1e-6 abs err.
      const float a = fmaf(winl, ut, h);
      float z;
      asm("v_exp_f32 %0, %1" : "=v"(z) : "v"(a * 2.885390082f));
      float r;
      asm("v_rcp_f32 %0, %1" : "=v"(r) : "v"(z + 1.0f));
      fresh[wv * ROWS_PER_WAVE + l] = fmaf(-2.0f, r, 1.0f);
    }
    __syncthreads();  // barrier 2: fresh[] complete

    // per-wave replica publish: wave wv stores the WG's full 32-row slice
    // to replica wv (8 parallel 256B full-line stores across the waves).
    if (wv < nrepl && l < ROWS_PER_WG) {
      const unsigned long long pk =
          ((unsigned long long)__float_as_uint(fresh[l]) << 32) | (unsigned)t;
      __hip_atomic_store(
          pairs + (size_t)wv * REPL + (t & 1) * HIDDEN + g * ROWS_PER_WG + l,
          pk, __ATOMIC_RELAXED, __HIP_MEMORY_SCOPE_AGENT);
    }
    if (wv == 1 && t >= WASHOUT) {
      // distributed readout: this WG's 32-row partial of x_t . w_out
      float part = (l < 32) ? fresh[l] * wol : 0.f;
      part += __shfl_xor(part, 32, 64);
      part += __shfl_xor(part, 16, 64);
      part += __shfl_xor(part, 8, 64);
      part += __shfl_xor(part, 4, 64);
      part += __shfl_xor(part, 2, 64);
      part += __shfl_xor(part, 1, 64);
      if (l == 0) atomicAdd(&out[t - WASHOUT], part);
    }
  }
}

extern "C" void kernel_launch(void* const* d_in, const int* in_sizes, int n_in,
                              void* d_out, int out_size, void* d_ws, size_t ws_size,
                              hipStream_t stream) {
  const float* u     = (const float*)d_in[0];
  const float* w_in  = (const float*)d_in[1];
  const float* w_res = (const float*)d_in[2];
  const float* w_out = (const float*)d_in[3];
  float* out = (float*)d_out;
  unsigned long long* pairs = (unsigned long long*)d_ws;

  // replicas need NREPL * 32 KB of ws; fall back to a single mailbox
  const int nrepl =
      (ws_size >= (size_t)NREPL * REPL * sizeof(unsigned long long)) ? NREPL : 1;

  // out accumulates atomicAdd partials -> must start at zero every call
  hipMemsetAsync(out, 0, (size_t)out_size * sizeof(float), stream);
  esn_main<<<NWG, NTHR, 0, stream>>>(u, w_in, w_res, w_out, out, pairs, nrepl);
}